// Round 1
// baseline (361.121 us; speedup 1.0000x reference)
//
#include <hip/hip_runtime.h>

namespace {
constexpr int Bc = 4, Hc = 16, Sc = 8192, Dc = 64, Mc = 64;
constexpr int NH = Bc * Hc;          // 64 heads
constexpr int TILE = 64;             // rows per tile
constexpr int CH = 512;              // rows per block
constexpr int TPT = CH / TILE;       // 8 tiles per block
constexpr int NCHUNK = Sc / CH;      // 16 chunks per head
constexpr int LDP = 68;              // padded LDS stride (words), 16B-aligned
constexpr int B1SZ = Mc * (Dc + 1);  // 4160 floats per head
}

// Phase 1: buf1[bh][m][c] = sum_s k'[s][m] * C[s][c],  C = [V, 1]
__global__ __launch_bounds__(256) void perf_phase1(
    const float* __restrict__ Kg, const float* __restrict__ Vg,
    const float* __restrict__ omega, float* __restrict__ buf1) {
  __shared__ float w[Dc * Mc];      // omega [d][m]
  __shared__ float KT[Dc * LDP];    // [d][row]; reused as KP[row][j]
  __shared__ float VL[TILE * LDP];  // [row][c]
  __shared__ float ssq[TILE];

  const int t = threadIdx.x;
  const int bh = blockIdx.x / NCHUNK;
  const int chunk = blockIdx.x % NCHUNK;
  const float* Kb = Kg + ((size_t)bh * Sc + (size_t)chunk * CH) * Dc;
  const float* Vb = Vg + ((size_t)bh * Sc + (size_t)chunk * CH) * Dc;

  {  // stage omega (row-major [d][m]), contiguous float4 copy
    const float4* src = (const float4*)omega;
    float4* dst = (float4*)w;
    for (int i = t; i < Dc * Mc / 4; i += 256) dst[i] = src[i];
  }

  const int tr = t >> 4;   // 0..15
  const int tc = t & 15;   // 0..15
  float acc[4][4] = {{0.f}};
  float dacc[4] = {0.f};

  __syncthreads();

  for (int tile = 0; tile < TPT; ++tile) {
    const float4* Kt = (const float4*)(Kb + (size_t)tile * TILE * Dc);
    const float4* Vt = (const float4*)(Vb + (size_t)tile * TILE * Dc);
#pragma unroll
    for (int rr = 0; rr < 4; ++rr) {
      int idx = rr * 256 + t;  // 0..1023 float4s
      int row = idx >> 4;      // 0..63
      int c4 = idx & 15;       // 0..15
      float4 kv = Kt[idx];
      KT[(c4 * 4 + 0) * LDP + row] = kv.x;
      KT[(c4 * 4 + 1) * LDP + row] = kv.y;
      KT[(c4 * 4 + 2) * LDP + row] = kv.z;
      KT[(c4 * 4 + 3) * LDP + row] = kv.w;
      float ps = kv.x * kv.x + kv.y * kv.y + kv.z * kv.z + kv.w * kv.w;
      ps += __shfl_xor(ps, 1, 64);
      ps += __shfl_xor(ps, 2, 64);
      ps += __shfl_xor(ps, 4, 64);
      ps += __shfl_xor(ps, 8, 64);
      if (c4 == 0) ssq[row] = ps;
      float4 vv = Vt[idx];
      *(float4*)&VL[row * LDP + c4 * 4] = vv;
    }
    __syncthreads();

    // GEMM1: x[i][k] = sum_d K[row=4tr+i][d] * w[d][j=4tc+k]
    float x[4][4] = {{0.f}};
#pragma unroll 4
    for (int d = 0; d < Dc; ++d) {
      float4 a = *(const float4*)&KT[d * LDP + tr * 4];
      float4 b = *(const float4*)&w[d * Mc + tc * 4];
      const float av[4] = {a.x, a.y, a.z, a.w};
      const float bv[4] = {b.x, b.y, b.z, b.w};
#pragma unroll
      for (int i = 0; i < 4; ++i)
#pragma unroll
        for (int k = 0; k < 4; ++k) x[i][k] = fmaf(av[i], bv[k], x[i][k]);
    }

    float kp[4][4];
#pragma unroll
    for (int i = 0; i < 4; ++i) {
      float hs = -0.5f * ssq[tr * 4 + i];
#pragma unroll
      for (int k = 0; k < 4; ++k) kp[i][k] = 0.125f * __expf(x[i][k] + hs);
    }
    __syncthreads();  // all GEMM1 reads of KT done before overwrite

    // write KP[row][j] into KT buffer
#pragma unroll
    for (int i = 0; i < 4; ++i)
      *(float4*)&KT[(tr * 4 + i) * LDP + tc * 4] =
          make_float4(kp[i][0], kp[i][1], kp[i][2], kp[i][3]);
    __syncthreads();

    // GEMM2: acc[i][k] += sum_row KP[row][j=4tr+i] * VL[row][c=4tc+k]
    //        dacc[i]   += sum_row KP[row][4tr+i]      (ones column)
#pragma unroll 4
    for (int r = 0; r < TILE; ++r) {
      float4 a = *(const float4*)&KT[r * LDP + tr * 4];
      float4 b = *(const float4*)&VL[r * LDP + tc * 4];
      const float av[4] = {a.x, a.y, a.z, a.w};
      const float bv[4] = {b.x, b.y, b.z, b.w};
#pragma unroll
      for (int i = 0; i < 4; ++i) {
        dacc[i] += av[i];
#pragma unroll
        for (int k = 0; k < 4; ++k) acc[i][k] = fmaf(av[i], bv[k], acc[i][k]);
      }
    }
    __syncthreads();  // before next tile restages KT/VL
  }

  float* b1 = buf1 + (size_t)bh * B1SZ;
#pragma unroll
  for (int i = 0; i < 4; ++i)
#pragma unroll
    for (int k = 0; k < 4; ++k)
      atomicAdd(&b1[(tr * 4 + i) * (Dc + 1) + tc * 4 + k], acc[i][k]);
  if (tc == 0) {
#pragma unroll
    for (int i = 0; i < 4; ++i)
      atomicAdd(&b1[(tr * 4 + i) * (Dc + 1) + Dc], dacc[i]);
  }
}

// Phase 2: out[s][c] = (sum_m q'[s][m] buf1[m][c]) / (sum_m q'[s][m] buf1[m][64])
__global__ __launch_bounds__(256) void perf_phase2(
    const float* __restrict__ Qg, const float* __restrict__ omega,
    const float* __restrict__ buf1, float* __restrict__ out) {
  __shared__ float w[Dc * Mc];
  __shared__ float QT[Dc * LDP];  // [d][row]; reused as QP[j][row]
  __shared__ float B1[Mc * LDP];  // [j][c], c = 0..64
  __shared__ float ssq[TILE];

  const int t = threadIdx.x;
  const int bh = blockIdx.x / NCHUNK;
  const int chunk = blockIdx.x % NCHUNK;
  const float* Qb = Qg + ((size_t)bh * Sc + (size_t)chunk * CH) * Dc;
  float* Ob = out + ((size_t)bh * Sc + (size_t)chunk * CH) * Dc;

  {
    const float4* src = (const float4*)omega;
    float4* dst = (float4*)w;
    for (int i = t; i < Dc * Mc / 4; i += 256) dst[i] = src[i];
  }
  {
    const float* b1 = buf1 + (size_t)bh * B1SZ;
    for (int i = t; i < B1SZ; i += 256) {
      int j = i / (Dc + 1), c = i % (Dc + 1);
      B1[j * LDP + c] = b1[i];
    }
  }
  const int tr = t >> 4;
  const int tc = t & 15;
  __syncthreads();

  for (int tile = 0; tile < TPT; ++tile) {
    const float4* Qt = (const float4*)(Qb + (size_t)tile * TILE * Dc);
#pragma unroll
    for (int rr = 0; rr < 4; ++rr) {
      int idx = rr * 256 + t;
      int row = idx >> 4;
      int c4 = idx & 15;
      float4 qv = Qt[idx];
      QT[(c4 * 4 + 0) * LDP + row] = qv.x;
      QT[(c4 * 4 + 1) * LDP + row] = qv.y;
      QT[(c4 * 4 + 2) * LDP + row] = qv.z;
      QT[(c4 * 4 + 3) * LDP + row] = qv.w;
      float ps = qv.x * qv.x + qv.y * qv.y + qv.z * qv.z + qv.w * qv.w;
      ps += __shfl_xor(ps, 1, 64);
      ps += __shfl_xor(ps, 2, 64);
      ps += __shfl_xor(ps, 4, 64);
      ps += __shfl_xor(ps, 8, 64);
      if (c4 == 0) ssq[row] = ps;
    }
    __syncthreads();

    float x[4][4] = {{0.f}};
#pragma unroll 4
    for (int d = 0; d < Dc; ++d) {
      float4 a = *(const float4*)&QT[d * LDP + tr * 4];
      float4 b = *(const float4*)&w[d * Mc + tc * 4];
      const float av[4] = {a.x, a.y, a.z, a.w};
      const float bv[4] = {b.x, b.y, b.z, b.w};
#pragma unroll
      for (int i = 0; i < 4; ++i)
#pragma unroll
        for (int k = 0; k < 4; ++k) x[i][k] = fmaf(av[i], bv[k], x[i][k]);
    }

    float qp[4][4];
#pragma unroll
    for (int i = 0; i < 4; ++i) {
      float hs = -0.5f * ssq[tr * 4 + i];
#pragma unroll
      for (int k = 0; k < 4; ++k) qp[i][k] = 0.125f * __expf(x[i][k] + hs);
    }
    __syncthreads();

    // write QP[j][row]: j = 4tc+k, rows 4tr..4tr+3 contiguous -> b128
#pragma unroll
    for (int k = 0; k < 4; ++k)
      *(float4*)&QT[(tc * 4 + k) * LDP + tr * 4] =
          make_float4(qp[0][k], qp[1][k], qp[2][k], qp[3][k]);
    __syncthreads();

    // GEMM2: o[i][k] = sum_j QP[j][row=4tr+i] * B1[j][c=4tc+k]
    //        den[i]  = sum_j QP[j][4tr+i] * B1[j][64]
    float o[4][4] = {{0.f}};
    float den[4] = {0.f};
#pragma unroll 4
    for (int j = 0; j < Mc; ++j) {
      float4 a = *(const float4*)&QT[j * LDP + tr * 4];
      float4 b = *(const float4*)&B1[j * LDP + tc * 4];
      float bd = B1[j * LDP + Dc];
      const float av[4] = {a.x, a.y, a.z, a.w};
      const float bv[4] = {b.x, b.y, b.z, b.w};
#pragma unroll
      for (int i = 0; i < 4; ++i) {
        den[i] = fmaf(av[i], bd, den[i]);
#pragma unroll
        for (int k = 0; k < 4; ++k) o[i][k] = fmaf(av[i], bv[k], o[i][k]);
      }
    }

#pragma unroll
    for (int i = 0; i < 4; ++i) {
      float inv = 1.0f / den[i];
      float4 res = make_float4(o[i][0] * inv, o[i][1] * inv,
                               o[i][2] * inv, o[i][3] * inv);
      *(float4*)&Ob[(size_t)(tile * TILE + tr * 4 + i) * Dc + tc * 4] = res;
    }
    __syncthreads();  // before next tile restages QT
  }
}

extern "C" void kernel_launch(void* const* d_in, const int* in_sizes, int n_in,
                              void* d_out, int out_size, void* d_ws, size_t ws_size,
                              hipStream_t stream) {
  const float* Q = (const float*)d_in[0];
  const float* K = (const float*)d_in[1];
  const float* V = (const float*)d_in[2];
  const float* omega = (const float*)d_in[3];
  float* out = (float*)d_out;
  float* buf1 = (float*)d_ws;

  // zero the buf1 accumulator (ws is poisoned / stale between calls)
  hipMemsetAsync(d_ws, 0, (size_t)NH * B1SZ * sizeof(float), stream);

  dim3 grid(NH * NCHUNK);  // 1024 blocks
  dim3 block(256);
  perf_phase1<<<grid, block, 0, stream>>>(K, V, omega, buf1);
  perf_phase2<<<grid, block, 0, stream>>>(Q, omega, buf1, out);
}

// Round 2
// 349.486 us; speedup vs baseline: 1.0333x; 1.0333x over previous
//
#include <hip/hip_runtime.h>

namespace {
constexpr int Bc = 4, Hc = 16, Sc = 8192, Dc = 64, Mc = 64;
constexpr int NH = Bc * Hc;          // 64 heads
constexpr int TILE = 64;             // rows per tile
constexpr int CH = 512;              // rows per block
constexpr int TPT = CH / TILE;       // 8 tiles per block
constexpr int NCHUNK = Sc / CH;      // 16 chunks per head
constexpr int LDP = 68;              // padded LDS stride (words), 272B = 16B-aligned
constexpr int B1SZ = Mc * (Dc + 1);  // 4160 floats per head
}

// Phase 1: buf1[bh][m][c] = sum_s k'[s][m] * C[s][c],  C = [V, 1]
__global__ __launch_bounds__(256, 2) void perf_phase1(
    const float* __restrict__ Kg, const float* __restrict__ Vg,
    const float* __restrict__ omega, float* __restrict__ buf1) {
  __shared__ float w[Dc * Mc];      // omega [d][m]
  __shared__ float KT[Dc * LDP];    // [d][row]
  __shared__ float KP[TILE * LDP];  // [row][m]
  __shared__ float VL[TILE * LDP];  // [row][c]
  __shared__ float ssq[TILE];
  __shared__ float dred[Mc * 17];   // ones-column reduction [m][tr]

  const int t = threadIdx.x;
  const int bh = blockIdx.x / NCHUNK;
  const int chunk = blockIdx.x % NCHUNK;
  const float* Kb = Kg + ((size_t)bh * Sc + (size_t)chunk * CH) * Dc;
  const float* Vb = Vg + ((size_t)bh * Sc + (size_t)chunk * CH) * Dc;

  {  // stage omega (row-major [d][m])
    const float4* src = (const float4*)omega;
    float4* dst = (float4*)w;
    for (int i = t; i < Dc * Mc / 4; i += 256) dst[i] = src[i];
  }

  const int tr = t >> 4;   // 0..15
  const int tc = t & 15;   // 0..15
  float acc[4][4] = {{0.f}};
  float dloc[4] = {0.f, 0.f, 0.f, 0.f};

  float4 kreg[4], vreg[4];  // prefetch registers (next tile)

  auto load_tile = [&](int tile) {
    const float4* Kt = (const float4*)(Kb + (size_t)tile * TILE * Dc);
    const float4* Vt = (const float4*)(Vb + (size_t)tile * TILE * Dc);
#pragma unroll
    for (int rr = 0; rr < 4; ++rr) {
      kreg[rr] = Kt[rr * 256 + t];
      vreg[rr] = Vt[rr * 256 + t];
    }
  };
  auto store_tile = [&]() {
#pragma unroll
    for (int rr = 0; rr < 4; ++rr) {
      int idx = rr * 256 + t;  // 0..1023 float4s
      int row = idx >> 4;      // 0..63
      int c4 = idx & 15;       // 0..15
      float4 kv = kreg[rr];
      KT[(c4 * 4 + 0) * LDP + row] = kv.x;
      KT[(c4 * 4 + 1) * LDP + row] = kv.y;
      KT[(c4 * 4 + 2) * LDP + row] = kv.z;
      KT[(c4 * 4 + 3) * LDP + row] = kv.w;
      float ps = kv.x * kv.x + kv.y * kv.y + kv.z * kv.z + kv.w * kv.w;
      ps += __shfl_xor(ps, 1, 64);
      ps += __shfl_xor(ps, 2, 64);
      ps += __shfl_xor(ps, 4, 64);
      ps += __shfl_xor(ps, 8, 64);
      if (c4 == 0) ssq[row] = ps;
      *(float4*)&VL[row * LDP + c4 * 4] = vreg[rr];
    }
  };

  load_tile(0);
  store_tile();
  __syncthreads();

  for (int tile = 0; tile < TPT; ++tile) {
    if (tile + 1 < TPT) load_tile(tile + 1);  // issue early; consumed after sync B

    // GEMM1: x[i][k] = sum_d K[row=4tr+i][d] * w[d][j=4tc+k]
    float x[4][4] = {{0.f}};
#pragma unroll 4
    for (int d = 0; d < Dc; ++d) {
      float4 a = *(const float4*)&KT[d * LDP + tr * 4];
      float4 b = *(const float4*)&w[d * Mc + tc * 4];
      const float av[4] = {a.x, a.y, a.z, a.w};
      const float bv[4] = {b.x, b.y, b.z, b.w};
#pragma unroll
      for (int i = 0; i < 4; ++i)
#pragma unroll
        for (int k = 0; k < 4; ++k) x[i][k] = fmaf(av[i], bv[k], x[i][k]);
    }

    float kp[4][4];
#pragma unroll
    for (int i = 0; i < 4; ++i) {
      float hs = -0.5f * ssq[tr * 4 + i];
#pragma unroll
      for (int k = 0; k < 4; ++k) {
        kp[i][k] = 0.125f * __expf(x[i][k] + hs);
        dloc[k] += kp[i][k];  // ones-column, hoisted out of GEMM2
      }
    }
#pragma unroll
    for (int i = 0; i < 4; ++i)
      *(float4*)&KP[(tr * 4 + i) * LDP + tc * 4] =
          make_float4(kp[i][0], kp[i][1], kp[i][2], kp[i][3]);
    __syncthreads();  // A: KP visible; all GEMM1 KT reads done

    // GEMM2: acc[i][k] += sum_row KP[row][m=4tr+i] * VL[row][c=4tc+k]
#pragma unroll 4
    for (int r = 0; r < TILE; ++r) {
      float4 a = *(const float4*)&KP[r * LDP + tr * 4];
      float4 b = *(const float4*)&VL[r * LDP + tc * 4];
      const float av[4] = {a.x, a.y, a.z, a.w};
      const float bv[4] = {b.x, b.y, b.z, b.w};
#pragma unroll
      for (int i = 0; i < 4; ++i)
#pragma unroll
        for (int k = 0; k < 4; ++k) acc[i][k] = fmaf(av[i], bv[k], acc[i][k]);
    }
    __syncthreads();  // B: all KP/VL reads done

    if (tile + 1 < TPT) store_tile();  // vmcnt wait lands here, latency hidden
    __syncthreads();  // C: staged data visible
  }

  // ones-column block reduction (once)
#pragma unroll
  for (int k = 0; k < 4; ++k) dred[(tc * 4 + k) * 17 + tr] = dloc[k];
  __syncthreads();

  float* b1 = buf1 + (size_t)bh * B1SZ;
#pragma unroll
  for (int i = 0; i < 4; ++i)
#pragma unroll
    for (int k = 0; k < 4; ++k)
      atomicAdd(&b1[(tr * 4 + i) * (Dc + 1) + tc * 4 + k], acc[i][k]);
  if (t < Mc) {
    float s = 0.f;
#pragma unroll
    for (int j = 0; j < 16; ++j) s += dred[t * 17 + j];
    atomicAdd(&b1[t * (Dc + 1) + Dc], s);
  }
}

// Phase 2: out[s][c] = (sum_m q'[s][m] buf1[m][c]) / (sum_m q'[s][m] buf1[m][64])
__global__ __launch_bounds__(256, 2) void perf_phase2(
    const float* __restrict__ Qg, const float* __restrict__ omega,
    const float* __restrict__ buf1, float* __restrict__ out) {
  __shared__ float w[Dc * Mc];
  __shared__ float QT[Dc * LDP];  // [d][row]
  __shared__ float QP[Mc * LDP];  // [j][row]
  __shared__ float B1[Mc * LDP];  // [j][c], c = 0..64
  __shared__ float ssq[TILE];

  const int t = threadIdx.x;
  const int bh = blockIdx.x / NCHUNK;
  const int chunk = blockIdx.x % NCHUNK;
  const float* Qb = Qg + ((size_t)bh * Sc + (size_t)chunk * CH) * Dc;
  float* Ob = out + ((size_t)bh * Sc + (size_t)chunk * CH) * Dc;

  {
    const float4* src = (const float4*)omega;
    float4* dst = (float4*)w;
    for (int i = t; i < Dc * Mc / 4; i += 256) dst[i] = src[i];
  }
  {
    const float* b1 = buf1 + (size_t)bh * B1SZ;
    for (int i = t; i < B1SZ; i += 256) {
      int j = i / (Dc + 1), c = i % (Dc + 1);
      B1[j * LDP + c] = b1[i];
    }
  }

  const int tr = t >> 4;
  const int tc = t & 15;
  float4 qreg[4];

  auto load_tile = [&](int tile) {
    const float4* Qt = (const float4*)(Qb + (size_t)tile * TILE * Dc);
#pragma unroll
    for (int rr = 0; rr < 4; ++rr) qreg[rr] = Qt[rr * 256 + t];
  };
  auto store_tile = [&]() {
#pragma unroll
    for (int rr = 0; rr < 4; ++rr) {
      int idx = rr * 256 + t;
      int row = idx >> 4;
      int c4 = idx & 15;
      float4 qv = qreg[rr];
      QT[(c4 * 4 + 0) * LDP + row] = qv.x;
      QT[(c4 * 4 + 1) * LDP + row] = qv.y;
      QT[(c4 * 4 + 2) * LDP + row] = qv.z;
      QT[(c4 * 4 + 3) * LDP + row] = qv.w;
      float ps = qv.x * qv.x + qv.y * qv.y + qv.z * qv.z + qv.w * qv.w;
      ps += __shfl_xor(ps, 1, 64);
      ps += __shfl_xor(ps, 2, 64);
      ps += __shfl_xor(ps, 4, 64);
      ps += __shfl_xor(ps, 8, 64);
      if (c4 == 0) ssq[row] = ps;
    }
  };

  load_tile(0);
  store_tile();
  __syncthreads();

  for (int tile = 0; tile < TPT; ++tile) {
    if (tile + 1 < TPT) load_tile(tile + 1);

    float x[4][4] = {{0.f}};
#pragma unroll 4
    for (int d = 0; d < Dc; ++d) {
      float4 a = *(const float4*)&QT[d * LDP + tr * 4];
      float4 b = *(const float4*)&w[d * Mc + tc * 4];
      const float av[4] = {a.x, a.y, a.z, a.w};
      const float bv[4] = {b.x, b.y, b.z, b.w};
#pragma unroll
      for (int i = 0; i < 4; ++i)
#pragma unroll
        for (int k = 0; k < 4; ++k) x[i][k] = fmaf(av[i], bv[k], x[i][k]);
    }

    float qp[4][4];
#pragma unroll
    for (int i = 0; i < 4; ++i) {
      float hs = -0.5f * ssq[tr * 4 + i];
#pragma unroll
      for (int k = 0; k < 4; ++k) qp[i][k] = 0.125f * __expf(x[i][k] + hs);
    }
    // QP[j=4tc+k][row]: rows 4tr..4tr+3 contiguous -> b128
#pragma unroll
    for (int k = 0; k < 4; ++k)
      *(float4*)&QP[(tc * 4 + k) * LDP + tr * 4] =
          make_float4(qp[0][k], qp[1][k], qp[2][k], qp[3][k]);
    __syncthreads();  // A: QP visible; all GEMM1 QT reads done

    // GEMM2: o[i][k] = sum_j QP[j][row=4tr+i] * B1[j][c=4tc+k]
    float o[4][4] = {{0.f}};
    float den[4] = {0.f, 0.f, 0.f, 0.f};
#pragma unroll 4
    for (int j = 0; j < Mc; ++j) {
      float4 a = *(const float4*)&QP[j * LDP + tr * 4];
      float4 b = *(const float4*)&B1[j * LDP + tc * 4];
      float bd = B1[j * LDP + Dc];
      const float av[4] = {a.x, a.y, a.z, a.w};
      const float bv[4] = {b.x, b.y, b.z, b.w};
#pragma unroll
      for (int i = 0; i < 4; ++i) {
        den[i] = fmaf(av[i], bd, den[i]);
#pragma unroll
        for (int k = 0; k < 4; ++k) o[i][k] = fmaf(av[i], bv[k], o[i][k]);
      }
    }

#pragma unroll
    for (int i = 0; i < 4; ++i) {
      float inv = 1.0f / den[i];
      float4 res = make_float4(o[i][0] * inv, o[i][1] * inv,
                               o[i][2] * inv, o[i][3] * inv);
      *(float4*)&Ob[(size_t)(tile * TILE + tr * 4 + i) * Dc + tc * 4] = res;
    }

    if (tile + 1 < TPT) store_tile();  // QT writes: all GEMM1 reads done at sync A
    __syncthreads();  // B: staged data + QP-read ordering for next iter
  }
}

extern "C" void kernel_launch(void* const* d_in, const int* in_sizes, int n_in,
                              void* d_out, int out_size, void* d_ws, size_t ws_size,
                              hipStream_t stream) {
  const float* Q = (const float*)d_in[0];
  const float* K = (const float*)d_in[1];
  const float* V = (const float*)d_in[2];
  const float* omega = (const float*)d_in[3];
  float* out = (float*)d_out;
  float* buf1 = (float*)d_ws;

  hipMemsetAsync(d_ws, 0, (size_t)NH * B1SZ * sizeof(float), stream);

  dim3 grid(NH * NCHUNK);  // 1024 blocks
  dim3 block(256);
  perf_phase1<<<grid, block, 0, stream>>>(K, V, omega, buf1);
  perf_phase2<<<grid, block, 0, stream>>>(Q, omega, buf1, out);
}

// Round 3
// 167.218 us; speedup vs baseline: 2.1596x; 2.0900x over previous
//
// Performer FAVOR+ on MI355X — R3: full MFMA (bf16x2-split, 3-product) rewrite.
// p0: split/transpose omega -> ws. p1: K,V -> B1[m][c] + den[m] (atomics).
// p2: Q -> out = (q'@B1)/ (q'@denv). All GEMMs on v_mfma_f32_16x16x32_bf16.
#include <hip/hip_runtime.h>

typedef short short8 __attribute__((ext_vector_type(8)));
typedef float f32x4 __attribute__((ext_vector_type(4)));

namespace {
constexpr int Sc = 8192, Dc = 64;
constexpr int NH = 64;                 // B*H heads
constexpr int CH = 512;                // rows per block
constexpr int TPT = CH / 64;           // 8 tiles of 64 rows
constexpr int NCHUNK = Sc / CH;        // 16
constexpr size_t DEN_OFF = (size_t)NH * 4096;            // floats
constexpr size_t WT_OFF_BYTES = (DEN_OFF + NH * 64) * 4; // bytes; 16B aligned
}

// f32 -> bf16 hi (RTNE) + bf16 lo (truncated residual)
__device__ __forceinline__ void bsplit(float x, short& hi, short& lo) {
  unsigned u = __builtin_bit_cast(unsigned, x);
  unsigned rh = (u + 0x7fffu + ((u >> 16) & 1u)) & 0xffff0000u;
  hi = (short)(rh >> 16);
  float res = x - __builtin_bit_cast(float, rh);
  lo = (short)(__builtin_bit_cast(unsigned, res) >> 16);
}
__device__ __forceinline__ unsigned pk2(short lo16, short hi16) {
  return (unsigned)(unsigned short)lo16 | ((unsigned)(unsigned short)hi16 << 16);
}

__global__ void p0(const float* __restrict__ omega, short* __restrict__ wT) {
  int i = blockIdx.x * 256 + threadIdx.x;
  if (i < 4096) {
    int m = i >> 6, d = i & 63;
    short hi, lo;
    bsplit(omega[d * 64 + m], hi, lo);
    wT[m * 64 + d] = hi;          // wT_hi[m][d]
    wT[4096 + m * 64 + d] = lo;   // wT_lo[m][d]
  }
}

// ---------------- Phase 1: B1[m][c] = sum_s k'[s][m] * V[s][c]; den[m] = sum_s k'[s][m]
__global__ __launch_bounds__(256, 2) void p1(
    const float* __restrict__ Kg, const float* __restrict__ Vg,
    const short* __restrict__ wT, float* __restrict__ b1, float* __restrict__ den) {
  __shared__ short Kh[64 * 72], Kl[64 * 72];   // K tile bf16 hi/lo, [row][d] stride 72
  __shared__ unsigned VT[64 * 64];             // V^T packed (hi|lo<<16), [c][s^swz]
  __shared__ short PTh[64 * 72], PTl[64 * 72]; // k'^T bf16, [m][s] stride 72
  __shared__ float ssq[64];

  const int t = threadIdx.x;
  const int lane = t & 63;
  const int w = t >> 6;        // wave 0..3
  const int a = lane & 15;
  const int g = lane >> 4;     // 0..3
  const int bh = blockIdx.x / NCHUNK, ch = blockIdx.x % NCHUNK;
  const float* Kb = Kg + ((size_t)bh * Sc + (size_t)ch * CH) * Dc;
  const float* Vb = Vg + ((size_t)bh * Sc + (size_t)ch * CH) * Dc;

  // omega B-frags in registers: lane holds w[d = 32ks+8g+j][m = 16mt+a]
  short8 wfh[4][2], wfl[4][2];
#pragma unroll
  for (int mt = 0; mt < 4; ++mt)
#pragma unroll
    for (int ks = 0; ks < 2; ++ks) {
      int off = (a + 16 * mt) * 64 + 32 * ks + 8 * g;
      wfh[mt][ks] = *(const short8*)(wT + off);
      wfl[mt][ks] = *(const short8*)(wT + 4096 + off);
    }

  float4 kreg[4], vreg[4];
  auto load_tile = [&](int tile) {
    const float4* Kt = (const float4*)(Kb + (size_t)tile * 64 * Dc);
    const float4* Vt = (const float4*)(Vb + (size_t)tile * 64 * Dc);
#pragma unroll
    for (int rr = 0; rr < 4; ++rr) {
      kreg[rr] = Kt[rr * 256 + t];
      vreg[rr] = Vt[rr * 256 + t];
    }
  };
  auto store_tile = [&]() {
#pragma unroll
    for (int rr = 0; rr < 4; ++rr) {
      int idx = rr * 256 + t;
      int row = idx >> 4;   // 0..63
      int c4 = idx & 15;
      float4 kv = kreg[rr];
      short h0, h1, h2, h3, l0, l1, l2, l3;
      bsplit(kv.x, h0, l0); bsplit(kv.y, h1, l1);
      bsplit(kv.z, h2, l2); bsplit(kv.w, h3, l3);
      uint2 uh, ul;
      uh.x = pk2(h0, h1); uh.y = pk2(h2, h3);
      ul.x = pk2(l0, l1); ul.y = pk2(l2, l3);
      *(uint2*)&Kh[row * 72 + c4 * 4] = uh;
      *(uint2*)&Kl[row * 72 + c4 * 4] = ul;
      float ps = kv.x * kv.x + kv.y * kv.y + kv.z * kv.z + kv.w * kv.w;
      ps += __shfl_xor(ps, 1, 64); ps += __shfl_xor(ps, 2, 64);
      ps += __shfl_xor(ps, 4, 64); ps += __shfl_xor(ps, 8, 64);
      if (c4 == 0) ssq[row] = ps;
      // V transpose into packed swizzled image
      float4 vv = vreg[rr];
      int swz = 8 * (c4 & 7);
      short vh_, vl_;
      bsplit(vv.x, vh_, vl_); VT[(4 * c4 + 0) * 64 + (row ^ swz)] = pk2(vh_, vl_);
      bsplit(vv.y, vh_, vl_); VT[(4 * c4 + 1) * 64 + (row ^ swz)] = pk2(vh_, vl_);
      bsplit(vv.z, vh_, vl_); VT[(4 * c4 + 2) * 64 + (row ^ swz)] = pk2(vh_, vl_);
      bsplit(vv.w, vh_, vl_); VT[(4 * c4 + 3) * 64 + (row ^ swz)] = pk2(vh_, vl_);
    }
  };

  f32x4 B1a[4];
#pragma unroll
  for (int ct = 0; ct < 4; ++ct) B1a[ct] = (f32x4){0.f, 0.f, 0.f, 0.f};
  float dpart[4] = {0.f, 0.f, 0.f, 0.f};

  load_tile(0);
  store_tile();
  __syncthreads();

  for (int tile = 0; tile < TPT; ++tile) {
    if (tile + 1 < TPT) load_tile(tile + 1);

    // GEMM1: X[s][m] = K @ omega   (3-product bf16 split)
    f32x4 X[4];
#pragma unroll
    for (int mt = 0; mt < 4; ++mt) X[mt] = (f32x4){0.f, 0.f, 0.f, 0.f};
#pragma unroll
    for (int ks = 0; ks < 2; ++ks) {
      short8 ah = *(const short8*)&Kh[(16 * w + a) * 72 + 32 * ks + 8 * g];
      short8 al = *(const short8*)&Kl[(16 * w + a) * 72 + 32 * ks + 8 * g];
#pragma unroll
      for (int mt = 0; mt < 4; ++mt) {
        X[mt] = __builtin_amdgcn_mfma_f32_16x16x32_bf16(ah, wfh[mt][ks], X[mt], 0, 0, 0);
        X[mt] = __builtin_amdgcn_mfma_f32_16x16x32_bf16(ah, wfl[mt][ks], X[mt], 0, 0, 0);
        X[mt] = __builtin_amdgcn_mfma_f32_16x16x32_bf16(al, wfh[mt][ks], X[mt], 0, 0, 0);
      }
    }

    // exp -> k'; split; write P^T; den partials
    float sq[4];
#pragma unroll
    for (int r = 0; r < 4; ++r) sq[r] = ssq[16 * w + 4 * g + r];
#pragma unroll
    for (int mt = 0; mt < 4; ++mt) {
      short ph[4], pl[4];
#pragma unroll
      for (int r = 0; r < 4; ++r) {
        float p = 0.125f * __expf(X[mt][r] - 0.5f * sq[r]);
        dpart[mt] += p;
        bsplit(p, ph[r], pl[r]);
      }
      uint2 uh, ul;
      uh.x = pk2(ph[0], ph[1]); uh.y = pk2(ph[2], ph[3]);
      ul.x = pk2(pl[0], pl[1]); ul.y = pk2(pl[2], pl[3]);
      *(uint2*)&PTh[(16 * mt + a) * 72 + 16 * w + 4 * g] = uh;
      *(uint2*)&PTl[(16 * mt + a) * 72 + 16 * w + 4 * g] = ul;
    }
    __syncthreads();  // A: PT visible, Kh reads done

    // GEMM2: B1 += P^T @ V
#pragma unroll
    for (int ks = 0; ks < 2; ++ks) {
      short8 pah = *(const short8*)&PTh[(16 * w + a) * 72 + 32 * ks + 8 * g];
      short8 pal = *(const short8*)&PTl[(16 * w + a) * 72 + 32 * ks + 8 * g];
#pragma unroll
      for (int ct = 0; ct < 4; ++ct) {
        int c = 16 * ct + a;
        int s0 = (32 * ks + 8 * g) ^ (8 * ((c >> 2) & 7));
        const unsigned* vp = &VT[c * 64 + s0];
        uint4 q0 = *(const uint4*)vp;
        uint4 q1 = *(const uint4*)(vp + 4);
        short8 vh, vl;
        vh[0] = (short)(q0.x & 0xffff); vl[0] = (short)(q0.x >> 16);
        vh[1] = (short)(q0.y & 0xffff); vl[1] = (short)(q0.y >> 16);
        vh[2] = (short)(q0.z & 0xffff); vl[2] = (short)(q0.z >> 16);
        vh[3] = (short)(q0.w & 0xffff); vl[3] = (short)(q0.w >> 16);
        vh[4] = (short)(q1.x & 0xffff); vl[4] = (short)(q1.x >> 16);
        vh[5] = (short)(q1.y & 0xffff); vl[5] = (short)(q1.y >> 16);
        vh[6] = (short)(q1.z & 0xffff); vl[6] = (short)(q1.z >> 16);
        vh[7] = (short)(q1.w & 0xffff); vl[7] = (short)(q1.w >> 16);
        B1a[ct] = __builtin_amdgcn_mfma_f32_16x16x32_bf16(pah, vh, B1a[ct], 0, 0, 0);
        B1a[ct] = __builtin_amdgcn_mfma_f32_16x16x32_bf16(pah, vl, B1a[ct], 0, 0, 0);
        B1a[ct] = __builtin_amdgcn_mfma_f32_16x16x32_bf16(pal, vh, B1a[ct], 0, 0, 0);
      }
    }
    __syncthreads();  // B: VT/PT reads done
    if (tile + 1 < TPT) store_tile();
    __syncthreads();  // C: staged data visible
  }

  float* b1h = b1 + (size_t)bh * 4096;
#pragma unroll
  for (int ct = 0; ct < 4; ++ct)
#pragma unroll
    for (int r = 0; r < 4; ++r)
      atomicAdd(&b1h[(16 * w + 4 * g + r) * 64 + 16 * ct + a], B1a[ct][r]);
#pragma unroll
  for (int mt = 0; mt < 4; ++mt) {
    float v = dpart[mt];
    v += __shfl_xor(v, 16, 64);
    v += __shfl_xor(v, 32, 64);
    if (g == 0) atomicAdd(&den[bh * 64 + 16 * mt + a], v);
  }
}

// ---------------- Phase 2: out[s][c] = (q' @ B1) / (q' @ den)
__global__ __launch_bounds__(256, 2) void p2(
    const float* __restrict__ Qg, const short* __restrict__ wT,
    const float* __restrict__ b1, const float* __restrict__ den,
    float* __restrict__ out) {
  __shared__ short Qh[64 * 72], Ql[64 * 72];
  __shared__ unsigned QP[64 * 68];             // q' packed (hi|lo), [s][m] stride 68
  __shared__ short B1h[64 * 72], B1l[64 * 72]; // B1^T bf16, [c][m] stride 72
  __shared__ float denv[64];
  __shared__ float ssq[64];

  const int t = threadIdx.x;
  const int lane = t & 63;
  const int w = t >> 6;
  const int a = lane & 15;
  const int g = lane >> 4;
  const int bh = blockIdx.x / NCHUNK, ch = blockIdx.x % NCHUNK;
  const float* Qb = Qg + ((size_t)bh * Sc + (size_t)ch * CH) * Dc;

  short8 wfh[4][2], wfl[4][2];
#pragma unroll
  for (int mt = 0; mt < 4; ++mt)
#pragma unroll
    for (int ks = 0; ks < 2; ++ks) {
      int off = (a + 16 * mt) * 64 + 32 * ks + 8 * g;
      wfh[mt][ks] = *(const short8*)(wT + off);
      wfl[mt][ks] = *(const short8*)(wT + 4096 + off);
    }

  // stage B1^T (bf16 split) + den vector
  const float* b1g = b1 + (size_t)bh * 4096;
  for (int i = t; i < 4096; i += 256) {
    int m = i >> 6, c = i & 63;
    short hi, lo;
    bsplit(b1g[i], hi, lo);
    B1h[c * 72 + m] = hi;
    B1l[c * 72 + m] = lo;
  }
  if (t < 64) denv[t] = den[bh * 64 + t];

  float4 qreg[4];
  auto load_tile = [&](int tile) {
    const float4* Qt = (const float4*)(Qb + (size_t)tile * 64 * Dc);
#pragma unroll
    for (int rr = 0; rr < 4; ++rr) qreg[rr] = Qt[rr * 256 + t];
  };
  auto store_tile = [&]() {
#pragma unroll
    for (int rr = 0; rr < 4; ++rr) {
      int idx = rr * 256 + t;
      int row = idx >> 4;
      int c4 = idx & 15;
      float4 kv = qreg[rr];
      short h0, h1, h2, h3, l0, l1, l2, l3;
      bsplit(kv.x, h0, l0); bsplit(kv.y, h1, l1);
      bsplit(kv.z, h2, l2); bsplit(kv.w, h3, l3);
      uint2 uh, ul;
      uh.x = pk2(h0, h1); uh.y = pk2(h2, h3);
      ul.x = pk2(l0, l1); ul.y = pk2(l2, l3);
      *(uint2*)&Qh[row * 72 + c4 * 4] = uh;
      *(uint2*)&Ql[row * 72 + c4 * 4] = ul;
      float ps = kv.x * kv.x + kv.y * kv.y + kv.z * kv.z + kv.w * kv.w;
      ps += __shfl_xor(ps, 1, 64); ps += __shfl_xor(ps, 2, 64);
      ps += __shfl_xor(ps, 4, 64); ps += __shfl_xor(ps, 8, 64);
      if (c4 == 0) ssq[row] = ps;
    }
  };

  load_tile(0);
  store_tile();
  __syncthreads();

  for (int tile = 0; tile < TPT; ++tile) {
    if (tile + 1 < TPT) load_tile(tile + 1);

    f32x4 X[4];
#pragma unroll
    for (int mt = 0; mt < 4; ++mt) X[mt] = (f32x4){0.f, 0.f, 0.f, 0.f};
#pragma unroll
    for (int ks = 0; ks < 2; ++ks) {
      short8 ah = *(const short8*)&Qh[(16 * w + a) * 72 + 32 * ks + 8 * g];
      short8 al = *(const short8*)&Ql[(16 * w + a) * 72 + 32 * ks + 8 * g];
#pragma unroll
      for (int mt = 0; mt < 4; ++mt) {
        X[mt] = __builtin_amdgcn_mfma_f32_16x16x32_bf16(ah, wfh[mt][ks], X[mt], 0, 0, 0);
        X[mt] = __builtin_amdgcn_mfma_f32_16x16x32_bf16(ah, wfl[mt][ks], X[mt], 0, 0, 0);
        X[mt] = __builtin_amdgcn_mfma_f32_16x16x32_bf16(al, wfh[mt][ks], X[mt], 0, 0, 0);
      }
    }

    float sq[4];
#pragma unroll
    for (int r = 0; r < 4; ++r) sq[r] = ssq[16 * w + 4 * g + r];
    float dv[4];
#pragma unroll
    for (int mt = 0; mt < 4; ++mt) dv[mt] = denv[16 * mt + a];
    float dn[4] = {0.f, 0.f, 0.f, 0.f};
#pragma unroll
    for (int mt = 0; mt < 4; ++mt) {
#pragma unroll
      for (int r = 0; r < 4; ++r) {
        float p = 0.125f * __expf(X[mt][r] - 0.5f * sq[r]);
        dn[r] = fmaf(p, dv[mt], dn[r]);
        short hi, lo;
        bsplit(p, hi, lo);
        QP[(16 * w + 4 * g + r) * 68 + 16 * mt + a] = pk2(hi, lo);
      }
    }
#pragma unroll
    for (int r = 0; r < 4; ++r) {
      dn[r] += __shfl_xor(dn[r], 1, 64);
      dn[r] += __shfl_xor(dn[r], 2, 64);
      dn[r] += __shfl_xor(dn[r], 4, 64);
      dn[r] += __shfl_xor(dn[r], 8, 64);
    }
    __syncthreads();  // A

    f32x4 O[4];
#pragma unroll
    for (int ct = 0; ct < 4; ++ct) O[ct] = (f32x4){0.f, 0.f, 0.f, 0.f};
#pragma unroll
    for (int ks = 0; ks < 2; ++ks) {
      const unsigned* qp = &QP[(16 * w + a) * 68 + 32 * ks + 8 * g];
      uint4 q0 = *(const uint4*)qp;
      uint4 q1 = *(const uint4*)(qp + 4);
      short8 qh, ql;
      qh[0] = (short)(q0.x & 0xffff); ql[0] = (short)(q0.x >> 16);
      qh[1] = (short)(q0.y & 0xffff); ql[1] = (short)(q0.y >> 16);
      qh[2] = (short)(q0.z & 0xffff); ql[2] = (short)(q0.z >> 16);
      qh[3] = (short)(q0.w & 0xffff); ql[3] = (short)(q0.w >> 16);
      qh[4] = (short)(q1.x & 0xffff); ql[4] = (short)(q1.x >> 16);
      qh[5] = (short)(q1.y & 0xffff); ql[5] = (short)(q1.y >> 16);
      qh[6] = (short)(q1.z & 0xffff); ql[6] = (short)(q1.z >> 16);
      qh[7] = (short)(q1.w & 0xffff); ql[7] = (short)(q1.w >> 16);
#pragma unroll
      for (int ct = 0; ct < 4; ++ct) {
        short8 bh_ = *(const short8*)&B1h[(16 * ct + a) * 72 + 32 * ks + 8 * g];
        short8 bl_ = *(const short8*)&B1l[(16 * ct + a) * 72 + 32 * ks + 8 * g];
        O[ct] = __builtin_amdgcn_mfma_f32_16x16x32_bf16(qh, bh_, O[ct], 0, 0, 0);
        O[ct] = __builtin_amdgcn_mfma_f32_16x16x32_bf16(qh, bl_, O[ct], 0, 0, 0);
        O[ct] = __builtin_amdgcn_mfma_f32_16x16x32_bf16(ql, bh_, O[ct], 0, 0, 0);
      }
    }

    float inv[4];
#pragma unroll
    for (int r = 0; r < 4; ++r) inv[r] = 1.0f / dn[r];
    float* ob = out + ((size_t)bh * Sc + (size_t)ch * CH + tile * 64 + 16 * w + 4 * g) * 64;
#pragma unroll
    for (int ct = 0; ct < 4; ++ct)
#pragma unroll
      for (int r = 0; r < 4; ++r)
        ob[r * 64 + 16 * ct + a] = O[ct][r] * inv[r];
    __syncthreads();  // B
    if (tile + 1 < TPT) store_tile();
    __syncthreads();  // C
  }
}

extern "C" void kernel_launch(void* const* d_in, const int* in_sizes, int n_in,
                              void* d_out, int out_size, void* d_ws, size_t ws_size,
                              hipStream_t stream) {
  const float* Q = (const float*)d_in[0];
  const float* K = (const float*)d_in[1];
  const float* V = (const float*)d_in[2];
  const float* omega = (const float*)d_in[3];
  float* outp = (float*)d_out;
  float* b1 = (float*)d_ws;
  float* den = b1 + DEN_OFF;
  short* wT = (short*)((char*)d_ws + WT_OFF_BYTES);

  hipMemsetAsync(d_ws, 0, WT_OFF_BYTES, stream);  // zero b1 + den
  p0<<<16, 256, 0, stream>>>(omega, wT);
  p1<<<NH * NCHUNK, 256, 0, stream>>>(K, V, wT, b1, den);
  p2<<<NH * NCHUNK, 256, 0, stream>>>(Q, wT, b1, den, outp);
}

// Round 4
// 146.558 us; speedup vs baseline: 2.4640x; 1.1410x over previous
//
// Performer FAVOR+ on MI355X — R4: conflict-free packed LDS (stride-68 u32,
// hi|lo bf16), v_perm unpack, XOR-swizzled V transpose, grid=512 (1 round).
#include <hip/hip_runtime.h>

typedef short short8 __attribute__((ext_vector_type(8)));
typedef float f32x4 __attribute__((ext_vector_type(4)));

namespace {
constexpr int Sc = 8192, Dc = 64;
constexpr int NH = 64;                 // B*H heads
constexpr int CH = 1024;               // rows per block
constexpr int TPT = CH / 64;           // 16 tiles of 64 rows
constexpr int NCHUNK = Sc / CH;        // 8
constexpr size_t DEN_OFF = (size_t)NH * 4096;            // floats
constexpr size_t WT_OFF_BYTES = (DEN_OFF + NH * 64) * 4; // bytes
}

// pack f32 -> (bf16_hi RTNE) | (bf16_lo residual) << 16
__device__ __forceinline__ unsigned pkhl(float x) {
  unsigned u = __builtin_bit_cast(unsigned, x);
  unsigned rh = (u + 0x7fffu + ((u >> 16) & 1u)) & 0xffff0000u;
  float res = x - __builtin_bit_cast(float, rh);
  return (rh >> 16) | (__builtin_bit_cast(unsigned, res) & 0xffff0000u);
}
__device__ __forceinline__ void bsplit(float x, short& hi, short& lo) {
  unsigned p = pkhl(x);
  hi = (short)(p & 0xffff);
  lo = (short)(p >> 16);
}
// extract 8 hi-bf16 (low16 of each u32) / 8 lo-bf16 (high16) via v_perm
__device__ __forceinline__ short8 exhi(uint4 q0, uint4 q1) {
  union { unsigned u[4]; short8 s; } r;
  r.u[0] = __builtin_amdgcn_perm(q0.y, q0.x, 0x05040100u);
  r.u[1] = __builtin_amdgcn_perm(q0.w, q0.z, 0x05040100u);
  r.u[2] = __builtin_amdgcn_perm(q1.y, q1.x, 0x05040100u);
  r.u[3] = __builtin_amdgcn_perm(q1.w, q1.z, 0x05040100u);
  return r.s;
}
__device__ __forceinline__ short8 exlo(uint4 q0, uint4 q1) {
  union { unsigned u[4]; short8 s; } r;
  r.u[0] = __builtin_amdgcn_perm(q0.y, q0.x, 0x07060302u);
  r.u[1] = __builtin_amdgcn_perm(q0.w, q0.z, 0x07060302u);
  r.u[2] = __builtin_amdgcn_perm(q1.y, q1.x, 0x07060302u);
  r.u[3] = __builtin_amdgcn_perm(q1.w, q1.z, 0x07060302u);
  return r.s;
}

__global__ void p0(const float* __restrict__ omega, short* __restrict__ wT) {
  int i = blockIdx.x * 256 + threadIdx.x;
  if (i < 4096) {
    int m = i >> 6, d = i & 63;
    short hi, lo;
    bsplit(omega[d * 64 + m], hi, lo);
    wT[m * 64 + d] = hi;          // wT_hi[m][d]
    wT[4096 + m * 64 + d] = lo;   // wT_lo[m][d]
  }
}

// ---------------- Phase 1: B1[m][c] = sum_s k'[s][m] V[s][c]; den[m] = sum_s k'[s][m]
__global__ __launch_bounds__(256, 2) void p1(
    const float* __restrict__ Kg, const float* __restrict__ Vg,
    const short* __restrict__ wT, float* __restrict__ b1, float* __restrict__ den) {
  __shared__ unsigned Kpk[64 * 68];  // K tile packed, [row][d] stride 68
  __shared__ unsigned VT[64 * 68];   // V^T packed, [c][s ^ 4*((c>>3)&7)]
  __shared__ unsigned PT[64 * 68];   // k'^T packed, [m][s] stride 68
  __shared__ float ssq[64];

  const int t = threadIdx.x;
  const int lane = t & 63;
  const int w = t >> 6;      // wave 0..3
  const int a = lane & 15;
  const int g = lane >> 4;   // 0..3
  const int bh = blockIdx.x / NCHUNK, ch = blockIdx.x % NCHUNK;
  const float* Kb = Kg + ((size_t)bh * Sc + (size_t)ch * CH) * Dc;
  const float* Vb = Vg + ((size_t)bh * Sc + (size_t)ch * CH) * Dc;

  // omega B-frags: lane holds w[d=32ks+8g+j][m=16mt+a]
  short8 wfh[4][2], wfl[4][2];
#pragma unroll
  for (int mt = 0; mt < 4; ++mt)
#pragma unroll
    for (int ks = 0; ks < 2; ++ks) {
      int off = (a + 16 * mt) * 64 + 32 * ks + 8 * g;
      wfh[mt][ks] = *(const short8*)(wT + off);
      wfl[mt][ks] = *(const short8*)(wT + 4096 + off);
    }

  float4 kreg[4], vreg[4];
  auto load_tile = [&](int tile) {
    const float4* Kt = (const float4*)(Kb + (size_t)tile * 64 * Dc);
    const float4* Vt = (const float4*)(Vb + (size_t)tile * 64 * Dc);
#pragma unroll
    for (int rr = 0; rr < 4; ++rr) {
      kreg[rr] = Kt[rr * 256 + t];
      vreg[rr] = Vt[rr * 256 + t];
    }
  };
  auto store_tile = [&]() {
#pragma unroll
    for (int rr = 0; rr < 4; ++rr) {
      int idx = rr * 256 + t;
      int row = idx >> 4;   // 0..63
      int c4 = idx & 15;
      float4 kv = kreg[rr];
      uint4 kp;
      kp.x = pkhl(kv.x); kp.y = pkhl(kv.y);
      kp.z = pkhl(kv.z); kp.w = pkhl(kv.w);
      *(uint4*)&Kpk[row * 68 + 4 * c4] = kp;  // uniform-8 banks
      float ps = kv.x * kv.x + kv.y * kv.y + kv.z * kv.z + kv.w * kv.w;
      ps += __shfl_xor(ps, 1, 64); ps += __shfl_xor(ps, 2, 64);
      ps += __shfl_xor(ps, 4, 64); ps += __shfl_xor(ps, 8, 64);
      if (c4 == 0) ssq[row] = ps;
      // V transpose, XOR-swizzled s (2-way writes)
      float4 vv = vreg[rr];
      int sw = row ^ (4 * ((c4 >> 1) & 7));
      VT[(4 * c4 + 0) * 68 + sw] = pkhl(vv.x);
      VT[(4 * c4 + 1) * 68 + sw] = pkhl(vv.y);
      VT[(4 * c4 + 2) * 68 + sw] = pkhl(vv.z);
      VT[(4 * c4 + 3) * 68 + sw] = pkhl(vv.w);
    }
  };

  f32x4 B1a[4];
#pragma unroll
  for (int ct = 0; ct < 4; ++ct) B1a[ct] = (f32x4){0.f, 0.f, 0.f, 0.f};
  float dpart[4] = {0.f, 0.f, 0.f, 0.f};

  load_tile(0);
  store_tile();
  __syncthreads();

  for (int tile = 0; tile < TPT; ++tile) {
    if (tile + 1 < TPT) load_tile(tile + 1);

    // GEMM1: X[s][m] = K @ omega (3-product split)
    f32x4 X[4];
#pragma unroll
    for (int mt = 0; mt < 4; ++mt) X[mt] = (f32x4){0.f, 0.f, 0.f, 0.f};
#pragma unroll
    for (int ks = 0; ks < 2; ++ks) {
      const unsigned* kb = &Kpk[(16 * w + a) * 68 + 32 * ks + 8 * g];
      uint4 q0 = *(const uint4*)kb;
      uint4 q1 = *(const uint4*)(kb + 4);
      short8 ah = exhi(q0, q1), al = exlo(q0, q1);
#pragma unroll
      for (int mt = 0; mt < 4; ++mt) {
        X[mt] = __builtin_amdgcn_mfma_f32_16x16x32_bf16(ah, wfh[mt][ks], X[mt], 0, 0, 0);
        X[mt] = __builtin_amdgcn_mfma_f32_16x16x32_bf16(ah, wfl[mt][ks], X[mt], 0, 0, 0);
        X[mt] = __builtin_amdgcn_mfma_f32_16x16x32_bf16(al, wfh[mt][ks], X[mt], 0, 0, 0);
      }
    }

    // exp -> k'; pack; write P^T; den partials
    float sq[4];
#pragma unroll
    for (int r = 0; r < 4; ++r) sq[r] = ssq[16 * w + 4 * g + r];
#pragma unroll
    for (int mt = 0; mt < 4; ++mt) {
      uint4 pp;
      float p_;
      p_ = 0.125f * __expf(X[mt][0] - 0.5f * sq[0]); dpart[mt] += p_; pp.x = pkhl(p_);
      p_ = 0.125f * __expf(X[mt][1] - 0.5f * sq[1]); dpart[mt] += p_; pp.y = pkhl(p_);
      p_ = 0.125f * __expf(X[mt][2] - 0.5f * sq[2]); dpart[mt] += p_; pp.z = pkhl(p_);
      p_ = 0.125f * __expf(X[mt][3] - 0.5f * sq[3]); dpart[mt] += p_; pp.w = pkhl(p_);
      *(uint4*)&PT[(16 * mt + a) * 68 + 16 * w + 4 * g] = pp;  // uniform-8
    }
    __syncthreads();  // A: PT visible, Kpk reads done

    // GEMM2: B1 += P^T @ V
#pragma unroll
    for (int ks = 0; ks < 2; ++ks) {
      const unsigned* pb = &PT[(16 * w + a) * 68 + 32 * ks + 8 * g];
      uint4 r0 = *(const uint4*)pb;
      uint4 r1 = *(const uint4*)(pb + 4);
      short8 pah = exhi(r0, r1), pal = exlo(r0, r1);
#pragma unroll
      for (int ct = 0; ct < 4; ++ct) {
        int c = 16 * ct + a;
        int kk4 = 4 * ((2 * ct + (a >> 3)) & 7);
        int s0 = (32 * ks + 8 * g) ^ kk4;
        int s1 = (32 * ks + 8 * g + 4) ^ kk4;
        const unsigned* vb = &VT[c * 68];
        uint4 v0 = *(const uint4*)(vb + s0);
        uint4 v1 = *(const uint4*)(vb + s1);
        short8 vh = exhi(v0, v1), vl = exlo(v0, v1);
        B1a[ct] = __builtin_amdgcn_mfma_f32_16x16x32_bf16(pah, vh, B1a[ct], 0, 0, 0);
        B1a[ct] = __builtin_amdgcn_mfma_f32_16x16x32_bf16(pah, vl, B1a[ct], 0, 0, 0);
        B1a[ct] = __builtin_amdgcn_mfma_f32_16x16x32_bf16(pal, vh, B1a[ct], 0, 0, 0);
      }
    }
    __syncthreads();  // B: VT/PT reads done
    if (tile + 1 < TPT) store_tile();
    __syncthreads();  // C: staged data visible
  }

  float* b1h = b1 + (size_t)bh * 4096;
#pragma unroll
  for (int ct = 0; ct < 4; ++ct)
#pragma unroll
    for (int r = 0; r < 4; ++r)
      atomicAdd(&b1h[(16 * w + 4 * g + r) * 64 + 16 * ct + a], B1a[ct][r]);
#pragma unroll
  for (int mt = 0; mt < 4; ++mt) {
    float v = dpart[mt];
    v += __shfl_xor(v, 16, 64);
    v += __shfl_xor(v, 32, 64);
    if (g == 0) atomicAdd(&den[bh * 64 + 16 * mt + a], v);
  }
}

// ---------------- Phase 2: out[s][c] = (q' @ B1) / (q' . den)
__global__ __launch_bounds__(256, 2) void p2(
    const float* __restrict__ Qg, const short* __restrict__ wT,
    const float* __restrict__ b1, const float* __restrict__ den,
    float* __restrict__ out) {
  __shared__ unsigned Qpk[64 * 68];           // Q tile packed [row][d]
  __shared__ unsigned QP[64 * 68];            // q' packed [s][m]
  __shared__ short B1h[64 * 72], B1l[64 * 72];// B1^T bf16 [c][m] stride 72
  __shared__ float denv[64];
  __shared__ float ssq[64];

  const int t = threadIdx.x;
  const int lane = t & 63;
  const int w = t >> 6;
  const int a = lane & 15;
  const int g = lane >> 4;
  const int bh = blockIdx.x / NCHUNK, ch = blockIdx.x % NCHUNK;
  const float* Qb = Qg + ((size_t)bh * Sc + (size_t)ch * CH) * Dc;

  short8 wfh[4][2], wfl[4][2];
#pragma unroll
  for (int mt = 0; mt < 4; ++mt)
#pragma unroll
    for (int ks = 0; ks < 2; ++ks) {
      int off = (a + 16 * mt) * 64 + 32 * ks + 8 * g;
      wfh[mt][ks] = *(const short8*)(wT + off);
      wfl[mt][ks] = *(const short8*)(wT + 4096 + off);
    }

  const float* b1g = b1 + (size_t)bh * 4096;
  for (int i = t; i < 4096; i += 256) {
    int m = i >> 6, c = i & 63;
    short hi, lo;
    bsplit(b1g[i], hi, lo);
    B1h[c * 72 + m] = hi;
    B1l[c * 72 + m] = lo;
  }
  if (t < 64) denv[t] = den[bh * 64 + t];

  float4 qreg[4];
  auto load_tile = [&](int tile) {
    const float4* Qt = (const float4*)(Qb + (size_t)tile * 64 * Dc);
#pragma unroll
    for (int rr = 0; rr < 4; ++rr) qreg[rr] = Qt[rr * 256 + t];
  };
  auto store_tile = [&]() {
#pragma unroll
    for (int rr = 0; rr < 4; ++rr) {
      int idx = rr * 256 + t;
      int row = idx >> 4;
      int c4 = idx & 15;
      float4 kv = qreg[rr];
      uint4 qp;
      qp.x = pkhl(kv.x); qp.y = pkhl(kv.y);
      qp.z = pkhl(kv.z); qp.w = pkhl(kv.w);
      *(uint4*)&Qpk[row * 68 + 4 * c4] = qp;
      float ps = kv.x * kv.x + kv.y * kv.y + kv.z * kv.z + kv.w * kv.w;
      ps += __shfl_xor(ps, 1, 64); ps += __shfl_xor(ps, 2, 64);
      ps += __shfl_xor(ps, 4, 64); ps += __shfl_xor(ps, 8, 64);
      if (c4 == 0) ssq[row] = ps;
    }
  };

  load_tile(0);
  store_tile();
  __syncthreads();

  for (int tile = 0; tile < TPT; ++tile) {
    if (tile + 1 < TPT) load_tile(tile + 1);

    f32x4 X[4];
#pragma unroll
    for (int mt = 0; mt < 4; ++mt) X[mt] = (f32x4){0.f, 0.f, 0.f, 0.f};
#pragma unroll
    for (int ks = 0; ks < 2; ++ks) {
      const unsigned* qb = &Qpk[(16 * w + a) * 68 + 32 * ks + 8 * g];
      uint4 q0 = *(const uint4*)qb;
      uint4 q1 = *(const uint4*)(qb + 4);
      short8 ah = exhi(q0, q1), al = exlo(q0, q1);
#pragma unroll
      for (int mt = 0; mt < 4; ++mt) {
        X[mt] = __builtin_amdgcn_mfma_f32_16x16x32_bf16(ah, wfh[mt][ks], X[mt], 0, 0, 0);
        X[mt] = __builtin_amdgcn_mfma_f32_16x16x32_bf16(ah, wfl[mt][ks], X[mt], 0, 0, 0);
        X[mt] = __builtin_amdgcn_mfma_f32_16x16x32_bf16(al, wfh[mt][ks], X[mt], 0, 0, 0);
      }
    }

    float sq[4];
#pragma unroll
    for (int r = 0; r < 4; ++r) sq[r] = ssq[16 * w + 4 * g + r];
    float dv[4];
#pragma unroll
    for (int mt = 0; mt < 4; ++mt) dv[mt] = denv[16 * mt + a];
    float dn[4] = {0.f, 0.f, 0.f, 0.f};
#pragma unroll
    for (int mt = 0; mt < 4; ++mt) {
#pragma unroll
      for (int r = 0; r < 4; ++r) {
        float p_ = 0.125f * __expf(X[mt][r] - 0.5f * sq[r]);
        dn[r] = fmaf(p_, dv[mt], dn[r]);
        QP[(16 * w + 4 * g + r) * 68 + 16 * mt + a] = pkhl(p_);  // 2-way
      }
    }
#pragma unroll
    for (int r = 0; r < 4; ++r) {
      dn[r] += __shfl_xor(dn[r], 1, 64);
      dn[r] += __shfl_xor(dn[r], 2, 64);
      dn[r] += __shfl_xor(dn[r], 4, 64);
      dn[r] += __shfl_xor(dn[r], 8, 64);
    }
    __syncthreads();  // A: QP visible, Qpk reads done

    f32x4 O[4];
#pragma unroll
    for (int ct = 0; ct < 4; ++ct) O[ct] = (f32x4){0.f, 0.f, 0.f, 0.f};
#pragma unroll
    for (int ks = 0; ks < 2; ++ks) {
      const unsigned* qb = &QP[(16 * w + a) * 68 + 32 * ks + 8 * g];
      uint4 r0 = *(const uint4*)qb;
      uint4 r1 = *(const uint4*)(qb + 4);
      short8 qh = exhi(r0, r1), ql = exlo(r0, r1);
#pragma unroll
      for (int ct = 0; ct < 4; ++ct) {
        short8 bh_ = *(const short8*)&B1h[(16 * ct + a) * 72 + 32 * ks + 8 * g];
        short8 bl_ = *(const short8*)&B1l[(16 * ct + a) * 72 + 32 * ks + 8 * g];
        O[ct] = __builtin_amdgcn_mfma_f32_16x16x32_bf16(qh, bh_, O[ct], 0, 0, 0);
        O[ct] = __builtin_amdgcn_mfma_f32_16x16x32_bf16(qh, bl_, O[ct], 0, 0, 0);
        O[ct] = __builtin_amdgcn_mfma_f32_16x16x32_bf16(ql, bh_, O[ct], 0, 0, 0);
      }
    }

    float inv[4];
#pragma unroll
    for (int r = 0; r < 4; ++r) inv[r] = 1.0f / dn[r];
    float* ob = out + ((size_t)bh * Sc + (size_t)ch * CH + tile * 64 + 16 * w + 4 * g) * 64;
#pragma unroll
    for (int ct = 0; ct < 4; ++ct)
#pragma unroll
      for (int r = 0; r < 4; ++r)
        ob[r * 64 + 16 * ct + a] = O[ct][r] * inv[r];
    __syncthreads();  // B: QP reads done
    if (tile + 1 < TPT) store_tile();
    __syncthreads();  // C
  }
}

extern "C" void kernel_launch(void* const* d_in, const int* in_sizes, int n_in,
                              void* d_out, int out_size, void* d_ws, size_t ws_size,
                              hipStream_t stream) {
  const float* Q = (const float*)d_in[0];
  const float* K = (const float*)d_in[1];
  const float* V = (const float*)d_in[2];
  const float* omega = (const float*)d_in[3];
  float* outp = (float*)d_out;
  float* b1 = (float*)d_ws;
  float* den = b1 + DEN_OFF;
  short* wT = (short*)((char*)d_ws + WT_OFF_BYTES);

  hipMemsetAsync(d_ws, 0, WT_OFF_BYTES, stream);  // zero b1 + den
  p0<<<16, 256, 0, stream>>>(omega, wT);
  p1<<<NH * NCHUNK, 256, 0, stream>>>(K, V, wT, b1, den);
  p2<<<NH * NCHUNK, 256, 0, stream>>>(Q, wT, b1, den, outp);
}